// Round 4
// baseline (351.816 us; speedup 1.0000x reference)
//
#include <hip/hip_runtime.h>
#include <math.h>

// ===========================================================================
// PCSQCNN fully fused: FRQI encode -> [QFT2D -> mux -> IQFT2D -> pool]^3
//                      -> |.|^2 -> linear
//
// Round 10: k1..k5 fused into ONE kernel (kfuse); state in "registers".
// Round 11: waves_per_eu(4,4) -> no effect (VGPR stayed 64, scratch stayed).
// Round 12: call-free (__sinf/__cosf) -> no effect. Theory falsified.
// Round 13 (this round): HAND-SCALARIZED STATE. Evidence: scratch traffic
//   = exactly sizeof(r[8][4]) per thread, VGPR=64 across all variants ->
//   the state alloca was never SROA-promoted (runtime k-indices at SROA
//   time; unroll happens later). Fix per guide rule #20: eight named
//   arrays r0..r7, every index compile-time-constant, loops over k
//   replaced by explicit 8-way macro expansion. Arithmetic, LDS addresses,
//   barriers, and op order byte-identical to round 12.
//
// U tables (k0): U0 stored transposed [y_st][x_st]; U1 unchanged;
// U2 stored [yam][cx][cy][xam] so all mux loads are 128B-contiguous/thread.
// Custom ownerships:
//   F  = {2j, 2j+1, 64+2j, 64+2j+1}
//   F4 = {s0*32+m, +16, +64, +80}, s0=j>>4, m=j&15
// ===========================================================================

#define PI_F 3.14159265358979323846f
#define P_ 128

__device__ __forceinline__ float2 cmul(float2 a, float2 b) {
    return make_float2(a.x * b.x - a.y * b.y, a.x * b.y + a.y * b.x);
}
__device__ __forceinline__ float2 cadd(float2 a, float2 b) {
    return make_float2(a.x + b.x, a.y + b.y);
}
__device__ __forceinline__ float2 scl(float2 a, float s) {
    return make_float2(a.x * s, a.y * s);
}
// DIF butterfly: u' = u+v ; v' = (u-v)*w
__device__ __forceinline__ void bfly_dif(float2& u, float2& v, float2 w) {
    float tx = u.x - v.x, ty = u.y - v.y;
    u.x += v.x; u.y += v.y;
    v.x = tx * w.x - ty * w.y;
    v.y = tx * w.y + ty * w.x;
}
__device__ __forceinline__ void bfly_dif1(float2& u, float2& v) {
    float tx = u.x - v.x, ty = u.y - v.y;
    u.x += v.x; u.y += v.y;
    v.x = tx; v.y = ty;
}
// DIT inverse butterfly: t = v*conj(w); u' = u+t ; v' = u-t
__device__ __forceinline__ void bfly_dit(float2& u, float2& v, float2 w) {
    float tx = v.x * w.x + v.y * w.y, ty = v.y * w.x - v.x * w.y;
    v.x = u.x - tx; v.y = u.y - ty;
    u.x += tx; u.y += ty;
}
__device__ __forceinline__ void bfly_dit1(float2& u, float2& v) {
    float tx = v.x, ty = v.y;
    v.x = u.x - tx; v.y = u.y - ty;
    u.x += tx; u.y += ty;
}

constexpr int clog2(int v) { return v <= 1 ? 0 : 1 + clog2(v >> 1); }

// LDS exchange address: line L (0..63 per plane), idx 0..127, XOR bank
// swizzle (bijective; GF(2)-rank-verified for all ownership patterns).
__device__ __forceinline__ int pf(int L, int idx) {
    int m = ((idx & 32) ? 13 : 0) ^ ((idx & 64) ? 22 : 0);
    return L * P_ + (idx ^ m);
}

// Ownership: segment size N (<=128), stride S. Thread j (0..31 per line) owns
// idx[q] = seg*N + 4S*(jj/S) + (jj%S) + S*q.  o = jj%S (twiddle low part).
template <int N, int S>
__device__ __forceinline__ void oidx(int j, int i[4], int& o) {
    constexpr int TPS = N / 4;
    constexpr int LT = clog2(TPS);
    int s = j >> LT;
    int jj = j & (TPS - 1);
    o = jj & (S - 1);
    int base = s * N + ((jj & ~(S - 1)) << 2) + o;
    i[0] = base; i[1] = base + S; i[2] = base + 2 * S; i[3] = base + 3 * S;
}

// Two DIF levels h=2S then h=S on r[0..3] (ownership stride S)
template <int S>
__device__ __forceinline__ void dif_pair(float2 r[4], int o, const float2* tw) {
    bfly_dif(r[0], r[2], tw[o * (32 / S)]);
    bfly_dif(r[1], r[3], tw[(o + S) * (32 / S)]);
    float2 wc = tw[o * (64 / S)];
    bfly_dif(r[0], r[1], wc);
    bfly_dif(r[2], r[3], wc);
}
// Two DIT levels h=S then h=2S
template <int S>
__device__ __forceinline__ void dit_pair(float2 r[4], int o, const float2* tw) {
    float2 wc = tw[o * (64 / S)];
    bfly_dit(r[0], r[1], wc);
    bfly_dit(r[2], r[3], wc);
    bfly_dit(r[0], r[2], tw[o * (32 / S)]);
    bfly_dit(r[1], r[3], tw[(o + S) * (32 / S)]);
}

// SoA store/load of one float2
__device__ __forceinline__ void stf(float* bx, float* by, int a, float2 v) {
    bx[a] = v.x; by[a] = v.y;
}
__device__ __forceinline__ float2 ldf(const float* bx, const float* by, int a) {
    return make_float2(bx[a], by[a]);
}

// One exchange round for a line pair (A -> LDS line la, B -> line lb).
// Crew = 32 consecutive lanes of one wave -> wave_barrier suffices.
// All indices compile-time-constant into A/B.
__device__ __forceinline__ void xch2(float* Xp, float* Yp, int la, int lb,
                                     const int* iw, const int* ir,
                                     float2 A[4], float2 B[4]) {
    stf(Xp, Yp, pf(la, iw[0]), A[0]); stf(Xp, Yp, pf(lb, iw[0]), B[0]);
    stf(Xp, Yp, pf(la, iw[1]), A[1]); stf(Xp, Yp, pf(lb, iw[1]), B[1]);
    stf(Xp, Yp, pf(la, iw[2]), A[2]); stf(Xp, Yp, pf(lb, iw[2]), B[2]);
    stf(Xp, Yp, pf(la, iw[3]), A[3]); stf(Xp, Yp, pf(lb, iw[3]), B[3]);
    __builtin_amdgcn_wave_barrier();
    A[0] = ldf(Xp, Yp, pf(la, ir[0])); B[0] = ldf(Xp, Yp, pf(lb, ir[0]));
    A[1] = ldf(Xp, Yp, pf(la, ir[1])); B[1] = ldf(Xp, Yp, pf(lb, ir[1]));
    A[2] = ldf(Xp, Yp, pf(la, ir[2])); B[2] = ldf(Xp, Yp, pf(lb, ir[2]));
    A[3] = ldf(Xp, Yp, pf(la, ir[3])); B[3] = ldf(Xp, Yp, pf(lb, ir[3]));
    __builtin_amdgcn_wave_barrier();
}

// Full 8-line crew exchange; rounds in the SAME order as the old xch8:
// (r0,r4), (r1,r5), (r2,r6), (r3,r7).
template <int NW, int SW, int NR, int SR>
__device__ __forceinline__ int xc8(float* Xp, float* Yp, int la, int lb, int j,
                                   float2 A0[4], float2 A1[4], float2 A2[4],
                                   float2 A3[4], float2 B0[4], float2 B1[4],
                                   float2 B2[4], float2 B3[4]) {
    int iw[4], ow, ir[4], orr;
    oidx<NW, SW>(j, iw, ow);
    oidx<NR, SR>(j, ir, orr);
    (void)ow;
    xch2(Xp, Yp, la, lb, iw, ir, A0, B0);
    xch2(Xp, Yp, la, lb, iw, ir, A1, B1);
    xch2(Xp, Yp, la, lb, iw, ir, A2, B2);
    xch2(Xp, Yp, la, lb, iw, ir, A3, B3);
    return orr;
}

__device__ __forceinline__ void mkF(int j, int* i) {
    i[0] = 2 * j; i[1] = 2 * j + 1; i[2] = 64 + 2 * j; i[3] = 65 + 2 * j;
}
__device__ __forceinline__ void mkF4(int j, int* i) {
    int b = (j >> 4) * 32 + (j & 15);
    i[0] = b; i[1] = b + 16; i[2] = b + 64; i[3] = b + 80;
}

// 2x2 multiplex on feature pair (a = f0, b = f1) with table entry U[0..3]
__device__ __forceinline__ void muxop(const float2* __restrict__ U,
                                      float2& a, float2& b) {
    float2 p0 = a, p1 = b;
    a = cadd(cmul(U[0], p0), cmul(U[1], p1));
    b = cadd(cmul(U[2], p0), cmul(U[3], p1));
}

// ---- 8-way expansion helpers (state = named arrays r0..r7) ----------------
#define FOR8(OP) { OP(r0) OP(r1) OP(r2) OP(r3) OP(r4) OP(r5) OP(r6) OP(r7) }
#define DIF8(S, O) { dif_pair<S>(r0, O, tw); dif_pair<S>(r1, O, tw); \
    dif_pair<S>(r2, O, tw); dif_pair<S>(r3, O, tw); dif_pair<S>(r4, O, tw); \
    dif_pair<S>(r5, O, tw); dif_pair<S>(r6, O, tw); dif_pair<S>(r7, O, tw); }
#define DIT8(S, O) { dit_pair<S>(r0, O, tw); dit_pair<S>(r1, O, tw); \
    dit_pair<S>(r2, O, tw); dit_pair<S>(r3, O, tw); dit_pair<S>(r4, O, tw); \
    dit_pair<S>(r5, O, tw); dit_pair<S>(r6, O, tw); dit_pair<S>(r7, O, tw); }
#define XC8(NW, SW, NR, SR) \
    xc8<NW, SW, NR, SR>(Xp, Yp, la, lb, j, r0, r1, r2, r3, r4, r5, r6, r7)
#define XCHC(IW, IR) { xch2(Xp, Yp, la, lb, IW, IR, r0, r4); \
    xch2(Xp, Yp, la, lb, IW, IR, r1, r5); \
    xch2(Xp, Yp, la, lb, IW, IR, r2, r6); \
    xch2(Xp, Yp, la, lb, IW, IR, r3, r7); }

// per-line op shapes (wA/wB/wC/sc_ taken from enclosing scope)
#define OP_H1F(R)  { bfly_dif1(R[0], R[1]); bfly_dif1(R[2], R[3]); }
#define OP_H1T(R)  { bfly_dit1(R[0], R[1]); bfly_dit1(R[2], R[3]); }
#define OP_H64(R)  { bfly_dit(R[0], R[2], wA); bfly_dit(R[1], R[3], wB); }
#define OP_FH(R)   { bfly_dif(R[0], R[1], wC); bfly_dif(R[2], R[3], wC); }
#define OP_H16P(R) { bfly_dit(R[0], R[1], wC); bfly_dit(R[2], R[3], wC); }
#define OP_SC(R)   { R[0] = scl(R[0], sc_); R[1] = scl(R[1], sc_); \
                     R[2] = scl(R[2], sc_); R[3] = scl(R[3], sc_); }

// register 4x4 transpose (pure renaming), per f-block
#define XPOSE_BLK(A, B, C, D) { float2 t_; \
    t_ = A[1]; A[1] = B[0]; B[0] = t_; \
    t_ = A[2]; A[2] = C[0]; C[0] = t_; \
    t_ = A[3]; A[3] = D[0]; D[0] = t_; \
    t_ = B[2]; B[2] = C[1]; C[1] = t_; \
    t_ = B[3]; B[3] = D[1]; D[1] = t_; \
    t_ = C[3]; C[3] = D[2]; D[2] = t_; }
#define XPOSE44() { XPOSE_BLK(r0, r1, r2, r3) XPOSE_BLK(r4, r5, r6, r7) }

// Transpose A chunk: store pair (RA,RB) at Y-positions isv, reload at new
// X-positions (MODE 0: Xl=j+32e ; MODE 1: Xl=2j+e). Rotation swizzle.
#define TPA_ST(R, XL) { const int Xl = (XL); \
    int a0 = Xl * P_ + ((isv[0] + Xl) & 127); Xp[a0] = R[0].x; Yp[a0] = R[0].y; \
    int a1 = Xl * P_ + ((isv[1] + Xl) & 127); Xp[a1] = R[1].x; Yp[a1] = R[1].y; \
    int a2 = Xl * P_ + ((isv[2] + Xl) & 127); Xp[a2] = R[2].x; Yp[a2] = R[2].y; \
    int a3 = Xl * P_ + ((isv[3] + Xl) & 127); Xp[a3] = R[3].x; Yp[a3] = R[3].y; }
#define TPA_LD(R, XL) { const int Xl = (XL); \
    R[0] = make_float2(Xp[Xl * P_ + ((g      + Xl) & 127)], Yp[Xl * P_ + ((g      + Xl) & 127)]); \
    R[1] = make_float2(Xp[Xl * P_ + ((g + 32 + Xl) & 127)], Yp[Xl * P_ + ((g + 32 + Xl) & 127)]); \
    R[2] = make_float2(Xp[Xl * P_ + ((g + 64 + Xl) & 127)], Yp[Xl * P_ + ((g + 64 + Xl) & 127)]); \
    R[3] = make_float2(Xp[Xl * P_ + ((g + 96 + Xl) & 127)], Yp[Xl * P_ + ((g + 96 + Xl) & 127)]); }
#define TPA_CHUNK(RA, RB, XLA, XLB) { \
    __syncthreads(); \
    TPA_ST(RA, g) TPA_ST(RB, g + 32) \
    __syncthreads(); \
    TPA_LD(RA, XLA) TPA_LD(RB, XLB) }

// Transpose B chunk: store pair at X-lines from isv (rotation swizzle with
// per-d offsets), reload at Y-positions idv.
#define TPB_ST(R, ISL) { const int Xl = (ISL) & 63; \
    int a0 = Xl * P_ + ((g      + Xl) & 127); Xp[a0] = R[0].x; Yp[a0] = R[0].y; \
    int a1 = Xl * P_ + ((g + 32 + Xl) & 127); Xp[a1] = R[1].x; Yp[a1] = R[1].y; \
    int a2 = Xl * P_ + ((g + 64 + Xl) & 127); Xp[a2] = R[2].x; Yp[a2] = R[2].y; \
    int a3 = Xl * P_ + ((g + 96 + Xl) & 127); Xp[a3] = R[3].x; Yp[a3] = R[3].y; }
#define TPB_LD(R, XL) { const int Xl = (XL); \
    R[0] = make_float2(Xp[Xl * P_ + ((idv[0] + Xl) & 127)], Yp[Xl * P_ + ((idv[0] + Xl) & 127)]); \
    R[1] = make_float2(Xp[Xl * P_ + ((idv[1] + Xl) & 127)], Yp[Xl * P_ + ((idv[1] + Xl) & 127)]); \
    R[2] = make_float2(Xp[Xl * P_ + ((idv[2] + Xl) & 127)], Yp[Xl * P_ + ((idv[2] + Xl) & 127)]); \
    R[3] = make_float2(Xp[Xl * P_ + ((idv[3] + Xl) & 127)], Yp[Xl * P_ + ((idv[3] + Xl) & 127)]); }
#define TPB_CHUNK(RA, RB, ISA, ISB) { \
    __syncthreads(); \
    TPB_ST(RA, ISA) TPB_ST(RB, ISB) \
    __syncthreads(); \
    TPB_LD(RA, g) TPB_LD(RB, g + 32) }

// ---------------------------------------------------------------------------
// K0: precompute multiplex U tables, pre-permuted by bit-reversal.
//   U0: TRANSPOSED  idx = y_st*128 + x_st
//   U1: unchanged   idx = ((cx*2+cy)*64 + xam)*64 + yam
//   U2: TRANSPOSED  idx = ((yam*2 + cx)*2 + cy)*32 + xam
// ---------------------------------------------------------------------------
__global__ __launch_bounds__(256) void k0_prep(const float* __restrict__ mux0,
                                               const float* __restrict__ mux1,
                                               const float* __restrict__ mux2,
                                               float2* __restrict__ U0,
                                               float2* __restrict__ U1,
                                               float2* __restrict__ U2) {
    int t = blockIdx.x * 256 + threadIdx.x;
    const float* src;
    float2* dst;
    if (t < 16384) {
        int xb = t >> 7, yb = t & 127;
        int rx = __brev((unsigned)xb) >> 25;
        int ry = __brev((unsigned)yb) >> 25;
        src = mux0 + ((size_t)rx * 128 + ry) * 3;
        dst = U0 + ((size_t)yb * 128 + xb) * 4;
    } else if (t < 32768) {
        int u = t - 16384;
        int yam = u & 63, xam = (u >> 6) & 63, cy = (u >> 12) & 1, cx = (u >> 13) & 1;
        int rx = __brev((unsigned)xam) >> 26;
        int ry = __brev((unsigned)yam) >> 26;
        src = mux1 + ((size_t)(((cx * 2 + cy) * 64 + rx) * 64 + ry)) * 3;
        dst = U1 + (size_t)u * 4;
    } else if (t < 36864) {
        int u = t - 32768;
        int yam = u & 31, xam = (u >> 5) & 31, cy = (u >> 10) & 1, cx = (u >> 11) & 1;
        int rx = __brev((unsigned)xam) >> 27;
        int ry = __brev((unsigned)yam) >> 27;
        src = mux2 + ((size_t)(((cx * 2 + cy) * 32 + rx) * 32 + ry)) * 3;
        dst = U2 + ((size_t)(((yam * 2 + cx) * 2 + cy) * 32 + xam)) * 4;
    } else {
        return;
    }
    float ax = src[0], ay = src[1], az = src[2];
    float r = sqrtf(ax * ax + ay * ay + az * az + 1e-20f);
    float cr = cosf(r);
    float snr = sinf(r) / r;
    dst[0] = make_float2(cr, -az * snr);
    dst[1] = make_float2(-ay * snr, -ax * snr);
    dst[2] = make_float2(ay * snr, -ax * snr);
    dst[3] = make_float2(cr, az * snr);
}

// ---------------------------------------------------------------------------
// KFUSE: whole pipeline per image. Block = 1024 threads (32 crews x 32).
// State: 8 named 4-float2 arrays (hand-scalarized, round 13).
// LDS (dynamic 66048 B): Xp[64*128] | Yp[64*128] | tw[64].
// ---------------------------------------------------------------------------
__global__ __attribute__((amdgpu_flat_work_group_size(1024, 1024)))
__attribute__((amdgpu_waves_per_eu(4, 4)))
void kfuse(const float* __restrict__ img,
           const float2* __restrict__ U0,
           const float2* __restrict__ U1,
           const float2* __restrict__ U2,
           float* __restrict__ prob) {
    extern __shared__ float smem[];
    float* Xp = smem;                       // 8192 floats
    float* Yp = smem + 8192;                // 8192 floats
    float2* tw = (float2*)(smem + 16384);   // 64 float2

    const int tid = threadIdx.x;
    const int b = blockIdx.x;
    const int g = tid >> 5;
    const int j = tid & 31;
    const int la = 2 * g, lb = 2 * g + 1;

    if (tid < 64) {
        float ang = -(2.0f * PI_F / 128.0f) * (float)tid;  // |ang| < 2pi
        tw[tid] = make_float2(__cosf(ang), __sinf(ang));
    }

    float2 r0[4], r1[4], r2[4], r3[4], r4[4], r5[4], r6[4], r7[4];
    int o;

    // ================= pass 1 (Y): FRQI encode + FFT_Y128 =================
    {
        const float* ib = img + (size_t)b * 16384;
        const float S128 = 1.0f / 128.0f;
#define ENC_K(K, RA, RB) { \
        const float* ip = ib + (g + 32 * (K)) * 128; \
        { float ang = 0.5f * PI_F * ip[j];      RA[0] = make_float2(__cosf(ang) * S128, 0.0f); RB[0] = make_float2(__sinf(ang) * S128, 0.0f); } \
        { float ang = 0.5f * PI_F * ip[j + 32]; RA[1] = make_float2(__cosf(ang) * S128, 0.0f); RB[1] = make_float2(__sinf(ang) * S128, 0.0f); } \
        { float ang = 0.5f * PI_F * ip[j + 64]; RA[2] = make_float2(__cosf(ang) * S128, 0.0f); RB[2] = make_float2(__sinf(ang) * S128, 0.0f); } \
        { float ang = 0.5f * PI_F * ip[j + 96]; RA[3] = make_float2(__cosf(ang) * S128, 0.0f); RB[3] = make_float2(__sinf(ang) * S128, 0.0f); } }
        ENC_K(0, r0, r4) ENC_K(1, r1, r5) ENC_K(2, r2, r6) ENC_K(3, r3, r7)
#undef ENC_K
    }
    __syncthreads();  // tw visible
    DIF8(32, j)                                   // h=64,32
    o = XC8(128, 32, 128, 8);
    DIF8(8, o)                                    // h=16,8
    o = XC8(128, 8, 128, 2);
    DIF8(2, o)                                    // h=4,2
    o = XC8(128, 2, 128, 1);
    FOR8(OP_H1F)                                  // h=1

    // ================= T_A1 (MODE 0) =================
    {
        int isv[4] = {4 * j, 4 * j + 1, 4 * j + 2, 4 * j + 3};
        TPA_CHUNK(r0, r1, j, j + 32)
        TPA_CHUNK(r2, r3, j, j + 32)
        TPA_CHUNK(r4, r5, j, j + 32)
        TPA_CHUNK(r6, r7, j, j + 32)
        __syncthreads();
        XPOSE44()
    }

    // ====== pass 2 (X): FFT_X128 -> M0 -> IFFT_X128 -> FFT_X64 ======
    DIF8(32, j)
    o = XC8(128, 32, 128, 8);
    DIF8(8, o)
    o = XC8(128, 8, 128, 2);
    DIF8(2, o)
    o = XC8(128, 2, 128, 1);
    FOR8(OP_H1F)
    // M0 at x_st = 4j+q, y_st = g+32k (register-local f pair)
    {
#define MUX0_K(K, RA, RB) { \
        const float2* Ub = U0 + ((size_t)(g + 32 * (K)) * 128 + 4 * j) * 4; \
        muxop(Ub + 0, RA[0], RB[0]); muxop(Ub + 4,  RA[1], RB[1]); \
        muxop(Ub + 8, RA[2], RB[2]); muxop(Ub + 12, RA[3], RB[3]); }
        MUX0_K(0, r0, r4) MUX0_K(1, r1, r5) MUX0_K(2, r2, r6) MUX0_K(3, r3, r7)
#undef MUX0_K
    }
    // IFFT_X128: [1,2] -> [4,8] -> [16,32] -> [64]
    DIT8(1, 0)
    o = XC8(128, 1, 128, 4);
    DIT8(4, o)
    o = XC8(128, 4, 128, 16);
    DIT8(16, o)
    o = XC8(128, 16, 128, 32);
    { const float2 wA = tw[o], wB = tw[o + 32]; FOR8(OP_H64) }   // h=64
    { const float2 wC = tw[2 * o]; FOR8(OP_FH) }                 // FFT64 h=32
    o = XC8(128, 32, 64, 8);
    DIF8(8, o)                                    // FFT64 h=16,8
    o = XC8(64, 8, 64, 2);
    DIF8(2, o)                                    // h=4,2
    {   // -> F ownership (needed by T_B1)
        int iw_[4], o_, ir_[4];
        oidx<64, 2>(j, iw_, o_);
        mkF(j, ir_);
        XCHC(iw_, ir_)
    }
    FOR8(OP_H1F)                                  // h=1
    { const float sc_ = 1.0f / 128.0f; FOR8(OP_SC) }  // IFFT128 norm

    // ================= T_B1 =================
    {
        int isv[4], idv[4];
        mkF(j, isv);
        idv[0] = 4 * j; idv[1] = 4 * j + 1; idv[2] = 4 * j + 2; idv[3] = 4 * j + 3;
        XPOSE44()
        TPB_CHUNK(r0, r1, isv[0], isv[1])
        TPB_CHUNK(r2, r3, isv[2], isv[3])
        TPB_CHUNK(r4, r5, isv[0], isv[1])
        TPB_CHUNK(r6, r7, isv[2], isv[3])
        __syncthreads();
    }

    // == pass 3 (Y): IFFT_Y128 -> FFT_Y64 -> M1 -> IFFT_Y64 -> FFT_Y32 ==
    DIT8(1, 0)
    o = XC8(128, 1, 128, 4);
    DIT8(4, o)
    o = XC8(128, 4, 128, 16);
    DIT8(16, o)
    o = XC8(128, 16, 128, 32);
    { const float2 wA = tw[o], wB = tw[o + 32]; FOR8(OP_H64) }
    { const float2 wC = tw[2 * o]; FOR8(OP_FH) }
    o = XC8(128, 32, 64, 8);
    DIF8(8, o)
    o = XC8(64, 8, 64, 2);
    DIF8(2, o)
    o = XC8(64, 2, 64, 1);
    FOR8(OP_H1F)
    // M1: y_st = s*64 + 4jj + q; lines x_st = g+32k
    {
        const int s = j >> 4, jj = j & 15;
#define MUX1_K(CX, KB, RA, RB) { \
        const int xam = g + 32 * (KB); \
        const float2* Ub = U1 + \
            ((size_t)(((((((CX) << 1) | s) << 6) | xam) << 6) | (4 * jj))) * 4; \
        muxop(Ub + 0, RA[0], RB[0]); muxop(Ub + 4,  RA[1], RB[1]); \
        muxop(Ub + 8, RA[2], RB[2]); muxop(Ub + 12, RA[3], RB[3]); }
        MUX1_K(0, 0, r0, r4) MUX1_K(0, 1, r1, r5)
        MUX1_K(1, 0, r2, r6) MUX1_K(1, 1, r3, r7)
#undef MUX1_K
    }
    // IFFT_Y64: [1,2] -> [4,8] -> [16,32]
    DIT8(1, 0)
    o = XC8(64, 1, 64, 4);
    DIT8(4, o)
    o = XC8(64, 4, 64, 16);
    DIT8(16, o)
    { const float2 wC = tw[4 * o]; FOR8(OP_FH) }  // fused FFT32 h=16
    o = XC8(64, 16, 32, 4);
    DIF8(4, o)                                    // FFT32 h=8,4
    o = XC8(32, 4, 32, 1);
    DIF8(1, 0)                                    // h=2,1
    { const float sc_ = 1.0f / 8192.0f; FOR8(OP_SC) }  // IFFT128*IFFT64

    // ================= T_A2 (MODE 1, dest positions = F) =================
    {
        int isv[4], o_;
        oidx<32, 1>(j, isv, o_);
        TPA_CHUNK(r0, r1, 2 * j, 2 * j + 1)
        TPA_CHUNK(r2, r3, 2 * j, 2 * j + 1)
        TPA_CHUNK(r4, r5, 2 * j, 2 * j + 1)
        TPA_CHUNK(r6, r7, 2 * j, 2 * j + 1)
        __syncthreads();
        XPOSE44()
    }

    // ====== pass 4 (X): IFFT_X64 -> FFT_X32 -> M2 -> IFFT_X32 ======
    FOR8(OP_H1T)                                  // h=1 at F (w=1)
    {
        int iw_[4], ir_[4], o_;
        mkF(j, iw_);
        oidx<64, 2>(j, ir_, o_);
        XCHC(iw_, ir_)
        o = o_;
    }
    DIT8(2, o)                                    // h=2,4
    o = XC8(64, 2, 64, 8);
    DIT8(8, o)                                    // h=8,16
    o = XC8(64, 8, 64, 16);
    { const float2 wA = tw[2 * o], wB = tw[2 * (o + 16)]; FOR8(OP_H64) }  // h=32
    { const float2 wC = tw[4 * o]; FOR8(OP_FH) }  // fused FFT32 h=16
    o = XC8(64, 16, 32, 4);
    DIF8(4, o)
    o = XC8(32, 4, 32, 1);
    DIF8(1, 0)
    // M2: x_st = s4*32 + 4jj8 + q; lines y_st = g+32k
    {
        const int s4 = j >> 3, jj8 = j & 7;
#define MUX2_K(KB, RA, RB) { \
        const float2* Ub = U2 + \
            ((size_t)((((g << 2) | ((s4 & 1) << 1) | (KB)) << 5) | (4 * jj8))) * 4; \
        muxop(Ub + 0, RA[0], RB[0]); muxop(Ub + 4,  RA[1], RB[1]); \
        muxop(Ub + 8, RA[2], RB[2]); muxop(Ub + 12, RA[3], RB[3]); }
        MUX2_K(0, r0, r4) MUX2_K(1, r1, r5) MUX2_K(0, r2, r6) MUX2_K(1, r3, r7)
#undef MUX2_K
    }
    // IFFT_X32: [1,2] -> [4,8] -> [16] (end at F4 for T_B2)
    DIT8(1, 0)
    o = XC8(32, 1, 32, 4);
    DIT8(4, o)
    {
        int iw_[4], o_, ir_[4];
        oidx<32, 4>(j, iw_, o_);
        mkF4(j, ir_);
        XCHC(iw_, ir_)
    }
    {
        const int m = j & 15;
        const float2 wC = tw[4 * m];
        FOR8(OP_H16P)                             // h=16
        const float sc_ = 1.0f / 2048.0f;         // IFFT64*IFFT32
        FOR8(OP_SC)
    }

    // ================= T_B2 =================
    {
        int isv[4], idv[4], o_;
        mkF4(j, isv);
        oidx<32, 1>(j, idv, o_);
        XPOSE44()
        TPB_CHUNK(r0, r1, isv[0], isv[1])
        TPB_CHUNK(r2, r3, isv[2], isv[3])
        TPB_CHUNK(r4, r5, isv[0], isv[1])
        TPB_CHUNK(r6, r7, isv[2], isv[3])
        __syncthreads();
    }

    // ========== pass 5 (Y): IFFT_Y32 + |.|^2 marginal ==========
    DIT8(1, 0)
    o = XC8(32, 1, 32, 4);
    DIT8(4, o)
    o = XC8(32, 4, 32, 8);
    { const float2 wA = tw[4 * o], wB = tw[4 * o + 32]; FOR8(OP_H64) }  // h=16
    // prob: sum over xc (in-thread lines) and yc (= j>>3, via shfl)
    {
#define SQ2(v) ((v).x * (v).x + (v).y * (v).y)
        float s00 = SQ2(r0[0]) + SQ2(r1[0]) + SQ2(r2[0]) + SQ2(r3[0]);
        float s01 = SQ2(r0[1]) + SQ2(r1[1]) + SQ2(r2[1]) + SQ2(r3[1]);
        float s02 = SQ2(r0[2]) + SQ2(r1[2]) + SQ2(r2[2]) + SQ2(r3[2]);
        float s03 = SQ2(r0[3]) + SQ2(r1[3]) + SQ2(r2[3]) + SQ2(r3[3]);
        float s10 = SQ2(r4[0]) + SQ2(r5[0]) + SQ2(r6[0]) + SQ2(r7[0]);
        float s11 = SQ2(r4[1]) + SQ2(r5[1]) + SQ2(r6[1]) + SQ2(r7[1]);
        float s12 = SQ2(r4[2]) + SQ2(r5[2]) + SQ2(r6[2]) + SQ2(r7[2]);
        float s13 = SQ2(r4[3]) + SQ2(r5[3]) + SQ2(r6[3]) + SQ2(r7[3]);
#undef SQ2
        s00 += __shfl_xor(s00, 8); s00 += __shfl_xor(s00, 16);
        s01 += __shfl_xor(s01, 8); s01 += __shfl_xor(s01, 16);
        s02 += __shfl_xor(s02, 8); s02 += __shfl_xor(s02, 16);
        s03 += __shfl_xor(s03, 8); s03 += __shfl_xor(s03, 16);
        s10 += __shfl_xor(s10, 8); s10 += __shfl_xor(s10, 16);
        s11 += __shfl_xor(s11, 8); s11 += __shfl_xor(s11, 16);
        s12 += __shfl_xor(s12, 8); s12 += __shfl_xor(s12, 16);
        s13 += __shfl_xor(s13, 8); s13 += __shfl_xor(s13, 16);
        if ((j >> 3) == 0) {
            const int jj = j & 7;
            const float C = 1.0f / 1024.0f;
            float2* pp = (float2*)(prob + (size_t)(b * 32 + g) * 64);
            pp[jj +  0] = make_float2(s00 * C, s10 * C);
            pp[jj +  8] = make_float2(s01 * C, s11 * C);
            pp[jj + 16] = make_float2(s02 * C, s12 * C);
            pp[jj + 24] = make_float2(s03 * C, s13 * C);
        }
    }
}

// ---------------------------------------------------------------------------
// K6: linear head, wave-shuffle reduction (unchanged).
// ---------------------------------------------------------------------------
__global__ __launch_bounds__(256) void k6_linear(const float* __restrict__ prob,
                                                 const float* __restrict__ W,
                                                 const float* __restrict__ bv,
                                                 float* __restrict__ out) {
    __shared__ float red[40];
    int b = blockIdx.x;
    int tid = threadIdx.x;
    float acc[10];
#pragma unroll
    for (int c = 0; c < 10; ++c) acc[c] = 0.0f;
    for (int j = tid; j < 2048; j += 256) {
        float p = prob[(size_t)b * 2048 + j];
#pragma unroll
        for (int c = 0; c < 10; ++c) acc[c] += p * W[c * 2048 + j];
    }
    int wv = tid >> 6, ln = tid & 63;
#pragma unroll
    for (int c = 0; c < 10; ++c) {
        float s = acc[c];
        for (int off = 32; off > 0; off >>= 1) s += __shfl_down(s, off);
        if (ln == 0) red[wv * 10 + c] = s;
    }
    __syncthreads();
    if (tid < 10)
        out[b * 10 + tid] =
            red[tid] + red[10 + tid] + red[20 + tid] + red[30 + tid] + bv[tid];
}

// ---------------------------------------------------------------------------
extern "C" void kernel_launch(void* const* d_in, const int* in_sizes, int n_in,
                              void* d_out, int out_size, void* d_ws,
                              size_t ws_size, hipStream_t stream) {
    const float* images = (const float*)d_in[0];
    const float* mux0 = (const float*)d_in[1];
    const float* mux1 = (const float*)d_in[2];
    const float* mux2 = (const float*)d_in[3];
    const float* W = (const float*)d_in[4];
    const float* bv = (const float*)d_in[5];
    float* out = (float*)d_out;

    float2* U0 = (float2*)d_ws;
    float2* U1 = U0 + 65536;
    float2* U2 = U1 + 65536;
    float* prob = (float*)(U2 + 16384);
    const size_t needed =
        (size_t)(65536 + 65536 + 16384) * sizeof(float2) +
        (size_t)512 * 2048 * sizeof(float);
    if (ws_size < needed) return;

    const int LDS_BYTES = (16384 + 128) * 4;  // Xp|Yp planes + tw = 66048 B

    k0_prep<<<144, 256, 0, stream>>>(mux0, mux1, mux2, U0, U1, U2);
    kfuse<<<512, 1024, LDS_BYTES, stream>>>(images, U0, U1, U2, prob);
    k6_linear<<<512, 256, 0, stream>>>(prob, W, bv, out);
}